// Round 4
// baseline (1510.301 us; speedup 1.0000x reference)
//
#include <hip/hip_runtime.h>

#define B_ 4
#define S_ 4096
#define IN_ 1024
#define H_ 16
#define D_ 64
#define OUT_ 1024
#define HD_ 1024   // H*D
#define M_ 16384   // B*S

typedef __bf16 bf16x8 __attribute__((ext_vector_type(8)));
typedef float floatx4 __attribute__((ext_vector_type(4)));
typedef float floatx2 __attribute__((ext_vector_type(2)));

static __device__ __forceinline__ unsigned short f2bf(float f) {
    unsigned int u = __builtin_bit_cast(unsigned int, f);
    u += 0x7fffu + ((u >> 16) & 1u);   // round-to-nearest-even
    return (unsigned short)(u >> 16);
}

// ---------------- cast fp32 -> bf16, vectorized x4 ----------------
__global__ void cast_f32_bf16(const float* __restrict__ src,
                              unsigned short* __restrict__ dst, int n4) {
    int i = blockIdx.x * blockDim.x + threadIdx.x;
    if (i < n4) {
        float4 v = ((const float4*)src)[i];
        ushort4 o;
        o.x = f2bf(v.x); o.y = f2bf(v.y); o.z = f2bf(v.z); o.w = f2bf(v.w);
        ((ushort4*)dst)[i] = o;
    }
}

// ---------------- bf16 MFMA GEMM: C[M,N] = A[M,K] * B[N,K]^T ----------------
#define LSTR 40
__global__ __launch_bounds__(256) void gemm_bt(
    const unsigned short* __restrict__ A,   // [M,K] bf16
    const unsigned short* __restrict__ Bm,  // [N,K] bf16
    float* __restrict__ C, int M, int N, int K) {
    __shared__ unsigned short As[128 * LSTR];
    __shared__ unsigned short Bs[128 * LSTR];
    const int t = threadIdx.x;
    const int lane = t & 63;
    const int wave = t >> 6;
    const int wm = wave >> 1, wn = wave & 1;
    const int m0 = blockIdx.y * 128;
    const int n0 = blockIdx.x * 128;
    const int l16 = lane & 15;
    const int quad = lane >> 4;

    floatx4 acc[4][4];
#pragma unroll
    for (int i = 0; i < 4; i++)
#pragma unroll
        for (int j = 0; j < 4; j++) acc[i][j] = (floatx4){0.f, 0.f, 0.f, 0.f};

    for (int k0 = 0; k0 < K; k0 += 32) {
#pragma unroll
        for (int it = 0; it < 2; it++) {
            int c = it * 256 + t;
            int row = c >> 2;
            int kc = c & 3;
            uint4 va = *(const uint4*)(A + (size_t)(m0 + row) * K + k0 + kc * 8);
            *(uint4*)(As + row * LSTR + kc * 8) = va;
            uint4 vb = *(const uint4*)(Bm + (size_t)(n0 + row) * K + k0 + kc * 8);
            *(uint4*)(Bs + row * LSTR + kc * 8) = vb;
        }
        __syncthreads();
        bf16x8 af[4], bfr[4];
#pragma unroll
        for (int i = 0; i < 4; i++)
            af[i] = *(const bf16x8*)(As + (wm * 64 + i * 16 + l16) * LSTR + quad * 8);
#pragma unroll
        for (int j = 0; j < 4; j++)
            bfr[j] = *(const bf16x8*)(Bs + (wn * 64 + j * 16 + l16) * LSTR + quad * 8);
#pragma unroll
        for (int i = 0; i < 4; i++)
#pragma unroll
            for (int j = 0; j < 4; j++)
                acc[i][j] = __builtin_amdgcn_mfma_f32_16x16x32_bf16(
                    af[i], bfr[j], acc[i][j], 0, 0, 0);
        __syncthreads();
    }
#pragma unroll
    for (int i = 0; i < 4; i++)
#pragma unroll
        for (int j = 0; j < 4; j++)
#pragma unroll
            for (int r = 0; r < 4; r++) {
                int row = m0 + wm * 64 + i * 16 + quad * 4 + r;
                int col = n0 + wn * 64 + j * 16 + l16;
                C[(size_t)row * N + col] = acc[i][j][r];
            }
}

// ---------------- sequential RNN scan (v4: head/block, batch/wave) ----------------
// 16 blocks (one per head h; all 4 batches share W[h]), 4 waves (wave = batch).
// Lane e owns output e and computes the full 64-element dot product itself:
// every ds_read_b128 is wave-uniform (pure broadcast), no reduction, no exec
// masks. Each barrier interval advances FOUR chain-steps (one per wave), so
// barrier + LDS latency are amortized 4x vs v3. h double-buffered in LDS;
// raw lgkm barrier per step keeps global prefetch/stores in flight.
__global__ __launch_bounds__(256, 1) void rnn_scan(
    const float* __restrict__ xp,      // [B,S,H,D] fp32 (GEMM1 output)
    const float* __restrict__ w_h,     // [H,D,D]
    const float* __restrict__ bias,    // [H,D]
    const float* __restrict__ h0,      // [B,H,D]
    unsigned short* __restrict__ y) {  // [B,S,H,D] bf16
    const int h = blockIdx.x;          // head
    const int tid = threadIdx.x;
    const int b = tid >> 6;            // wave index = batch
    const int e = tid & 63;            // output element

    __shared__ __align__(16) float hbuf[4][2][64];   // [batch][buf][dim]

    // W[h][e][0..63] as 32 packed float2 (identical across the 4 waves)
    floatx2 W2[32];
    const float* wrow = w_h + ((size_t)(h * 64 + e)) * 64;
#pragma unroll
    for (int q = 0; q < 16; q++) {
        float4 v = ((const float4*)wrow)[q];
        W2[2 * q]     = (floatx2){v.x, v.y};
        W2[2 * q + 1] = (floatx2){v.z, v.w};
    }
    const float be = bias[h * 64 + e];
    hbuf[b][0][e] = h0[(b * 16 + h) * 64 + e];
    __syncthreads();

    const float* xb = xp + ((size_t)(b * S_) * 16 + h) * 64 + e;  // + t*1024
    unsigned short* yb = y + ((size_t)(b * S_) * 16 + h) * 64 + e;

    float xA[8], xB[8];
#pragma unroll
    for (int i2 = 0; i2 < 8; i2++) xA[i2] = xb[(size_t)i2 * 1024];
#pragma unroll
    for (int i2 = 0; i2 < 8; i2++) xB[i2] = xb[(size_t)(8 + i2) * 1024];

    auto step = [&](int r, int t, float xv) {
        const float4* h4 = (const float4*)hbuf[b][r];  // wave-uniform address
        floatx2 acc[8];
#pragma unroll
        for (int i = 0; i < 8; i++) acc[i] = (floatx2){0.f, 0.f};
#pragma unroll
        for (int q = 0; q < 16; q++) {
            float4 v = h4[q];  // broadcast ds_read_b128
            acc[(2 * q) & 7]     = __builtin_elementwise_fma(
                W2[2 * q],     (floatx2){v.x, v.y}, acc[(2 * q) & 7]);
            acc[(2 * q + 1) & 7] = __builtin_elementwise_fma(
                W2[2 * q + 1], (floatx2){v.z, v.w}, acc[(2 * q + 1) & 7]);
        }
        floatx2 s2 = ((acc[0] + acc[1]) + (acc[2] + acc[3])) +
                     ((acc[4] + acc[5]) + (acc[6] + acc[7]));
        float pre = (s2.x + s2.y) + (be + xv);
        // tanh: em = 2^(-2*log2e*|pre|); hn = sign * (1-em)/(1+em)
        float em = __builtin_amdgcn_exp2f(fabsf(pre) * -2.885390081777927f);
        float rr = (1.0f - em) * __builtin_amdgcn_rcpf(1.0f + em);
        float hn = copysignf(rr, pre);
        hbuf[b][1 - r][e] = hn;        // all 64 lanes, distinct dwords, no mask
        yb[(size_t)t * 1024] = f2bf(hn);
        // raw barrier: drain own DS ops (lgkmcnt), sync waves. NOT
        // __syncthreads(): no vmcnt(0) drain -> x prefetch / y stores stay
        // outstanding across steps.
        asm volatile("s_waitcnt lgkmcnt(0)\n\ts_barrier" ::: "memory");
    };

    for (int t0 = 0; t0 < S_; t0 += 16) {
#pragma unroll
        for (int u = 0; u < 8; u++) step(u & 1, t0 + u, xA[u]);
        if (t0 + 16 < S_) {
#pragma unroll
            for (int i2 = 0; i2 < 8; i2++) xA[i2] = xb[(size_t)(t0 + 16 + i2) * 1024];
        }
#pragma unroll
        for (int u = 0; u < 8; u++) step(u & 1, t0 + 8 + u, xB[u]);
        if (t0 + 24 < S_) {
#pragma unroll
            for (int i2 = 0; i2 < 8; i2++) xB[i2] = xb[(size_t)(t0 + 24 + i2) * 1024];
        }
    }
}

extern "C" void kernel_launch(void* const* d_in, const int* in_sizes, int n_in,
                              void* d_out, int out_size, void* d_ws, size_t ws_size,
                              hipStream_t stream) {
    const float* x     = (const float*)d_in[0];  // [B,S,IN]
    const float* h0    = (const float*)d_in[1];  // [B,H,D]
    const float* w_in  = (const float*)d_in[2];  // [HD,IN]
    const float* w_h   = (const float*)d_in[3];  // [H,D,D]
    const float* bias  = (const float*)d_in[4];  // [H,D]
    const float* w_out = (const float*)d_in[5];  // [OUT,HD]
    float* out = (float*)d_out;                  // [B,S,OUT] fp32; doubles as xp scratch

    char* ws = (char*)d_ws;
    unsigned short* x_bf    = (unsigned short*)(ws);                       // 33.5 MB
    unsigned short* win_bf  = (unsigned short*)(ws + (size_t)33554432);    // 2 MB
    unsigned short* wout_bf = (unsigned short*)(ws + (size_t)35651584);    // 2 MB
    unsigned short* y_bf    = (unsigned short*)(ws + (size_t)37748736);    // 33.5 MB

    {
        int n4 = (M_ * IN_) / 4;
        cast_f32_bf16<<<(n4 + 255) / 256, 256, 0, stream>>>(x, x_bf, n4);
        int w4 = (HD_ * IN_) / 4;
        cast_f32_bf16<<<(w4 + 255) / 256, 256, 0, stream>>>(w_in, win_bf, w4);
        cast_f32_bf16<<<(w4 + 255) / 256, 256, 0, stream>>>(w_out, wout_bf, w4);
    }
    // GEMM1: xp = x @ w_in^T  -> stored in d_out as scratch
    dim3 g1(HD_ / 128, M_ / 128);
    gemm_bt<<<g1, 256, 0, stream>>>(x_bf, win_bf, out, M_, HD_, IN_);
    // sequential scan: reads xp (d_out), writes y_bf
    rnn_scan<<<16, 256, 0, stream>>>(out, w_h, bias, h0, y_bf);
    // GEMM2: out = y @ w_out^T  -> overwrites d_out
    dim3 g2(OUT_ / 128, M_ / 128);
    gemm_bt<<<g2, 256, 0, stream>>>(y_bf, wout_bf, out, M_, OUT_, HD_);
}

// Round 5
// 1097.628 us; speedup vs baseline: 1.3760x; 1.3760x over previous
//
#include <hip/hip_runtime.h>

#define B_ 4
#define S_ 4096
#define IN_ 1024
#define H_ 16
#define D_ 64
#define OUT_ 1024
#define HD_ 1024   // H*D
#define M_ 16384   // B*S

typedef __bf16 bf16x8 __attribute__((ext_vector_type(8)));
typedef __bf16 bf16x2 __attribute__((ext_vector_type(2)));
typedef float floatx4 __attribute__((ext_vector_type(4)));
typedef float floatx2 __attribute__((ext_vector_type(2)));

static __device__ __forceinline__ unsigned short f2bf(float f) {
    unsigned int u = __builtin_bit_cast(unsigned int, f);
    u += 0x7fffu + ((u >> 16) & 1u);   // round-to-nearest-even
    return (unsigned short)(u >> 16);
}

// v_dot2_f32_bf16: c += a.x*b.x + a.y*b.y  (bf16 in, fp32 acc)
static __device__ __forceinline__ float dot2bf(unsigned int a, unsigned int b, float c) {
    return __builtin_amdgcn_fdot2_f32_bf16(__builtin_bit_cast(bf16x2, a),
                                           __builtin_bit_cast(bf16x2, b), c, false);
}

// quad_perm butterfly add via DPP (pure VALU, no LDS)
template <int CTRL>
static __device__ __forceinline__ float qadd(float v) {
    int s = __builtin_amdgcn_update_dpp(0, __builtin_bit_cast(int, v),
                                        CTRL, 0xF, 0xF, true);
    return v + __builtin_bit_cast(float, s);
}

// ---------------- cast fp32 -> bf16, vectorized x4 ----------------
__global__ void cast_f32_bf16(const float* __restrict__ src,
                              unsigned short* __restrict__ dst, int n4) {
    int i = blockIdx.x * blockDim.x + threadIdx.x;
    if (i < n4) {
        float4 v = ((const float4*)src)[i];
        ushort4 o;
        o.x = f2bf(v.x); o.y = f2bf(v.y); o.z = f2bf(v.z); o.w = f2bf(v.w);
        ((ushort4*)dst)[i] = o;
    }
}

// ---------------- bf16 MFMA GEMM: C[M,N] = A[M,K] * B[N,K]^T ----------------
#define LSTR 40
__global__ __launch_bounds__(256) void gemm_bt(
    const unsigned short* __restrict__ A,   // [M,K] bf16
    const unsigned short* __restrict__ Bm,  // [N,K] bf16
    float* __restrict__ C, int M, int N, int K) {
    __shared__ unsigned short As[128 * LSTR];
    __shared__ unsigned short Bs[128 * LSTR];
    const int t = threadIdx.x;
    const int lane = t & 63;
    const int wave = t >> 6;
    const int wm = wave >> 1, wn = wave & 1;
    const int m0 = blockIdx.y * 128;
    const int n0 = blockIdx.x * 128;
    const int l16 = lane & 15;
    const int quad = lane >> 4;

    floatx4 acc[4][4];
#pragma unroll
    for (int i = 0; i < 4; i++)
#pragma unroll
        for (int j = 0; j < 4; j++) acc[i][j] = (floatx4){0.f, 0.f, 0.f, 0.f};

    for (int k0 = 0; k0 < K; k0 += 32) {
#pragma unroll
        for (int it = 0; it < 2; it++) {
            int c = it * 256 + t;
            int row = c >> 2;
            int kc = c & 3;
            uint4 va = *(const uint4*)(A + (size_t)(m0 + row) * K + k0 + kc * 8);
            *(uint4*)(As + row * LSTR + kc * 8) = va;
            uint4 vb = *(const uint4*)(Bm + (size_t)(n0 + row) * K + k0 + kc * 8);
            *(uint4*)(Bs + row * LSTR + kc * 8) = vb;
        }
        __syncthreads();
        bf16x8 af[4], bfr[4];
#pragma unroll
        for (int i = 0; i < 4; i++)
            af[i] = *(const bf16x8*)(As + (wm * 64 + i * 16 + l16) * LSTR + quad * 8);
#pragma unroll
        for (int j = 0; j < 4; j++)
            bfr[j] = *(const bf16x8*)(Bs + (wn * 64 + j * 16 + l16) * LSTR + quad * 8);
#pragma unroll
        for (int i = 0; i < 4; i++)
#pragma unroll
            for (int j = 0; j < 4; j++)
                acc[i][j] = __builtin_amdgcn_mfma_f32_16x16x32_bf16(
                    af[i], bfr[j], acc[i][j], 0, 0, 0);
        __syncthreads();
    }
#pragma unroll
    for (int i = 0; i < 4; i++)
#pragma unroll
        for (int j = 0; j < 4; j++)
#pragma unroll
            for (int r = 0; r < 4; r++) {
                int row = m0 + wm * 64 + i * 16 + quad * 4 + r;
                int col = n0 + wn * 64 + j * 16 + l16;
                C[(size_t)row * N + col] = acc[i][j][r];
            }
}

// ---------------- sequential RNN scan (v5: v3 skeleton + bf16 h + dot2) ----
// 64 blocks (one (b,h) chain), 4 waves. Lane l: eo=l>>2 (output), p=l&3
// (16-elem k-slice). h stored in LDS as bf16 (128 B): per-CU DS traffic is
// 8 ds_read_b128 + 4 ds_write_b16 per step (v3 had 16 reads — DS-pipe issue
// at ~12cyc/b128 is the measured bottleneck, v4 post-mortem). MACs via
// v_dot2_f32_bf16 (2 MACs/instr, fp32 acc). Quad DPP butterfly reduces the
// 4 slices; raw lgkm barrier keeps global prefetch/stores in flight.
__global__ __launch_bounds__(256, 1) void rnn_scan(
    const float* __restrict__ xp,      // [B,S,H,D] fp32 (GEMM1 output)
    const float* __restrict__ w_h,     // [H,D,D]
    const float* __restrict__ bias,    // [H,D]
    const float* __restrict__ h0,      // [B,H,D]
    unsigned short* __restrict__ y) {  // [B,S,H,D] bf16
    const int bh = blockIdx.x;
    const int b = bh >> 4;
    const int h = bh & 15;
    const int tid = threadIdx.x;
    const int w = tid >> 6;
    const int l = tid & 63;
    const int eo = l >> 2;
    const int p = l & 3;
    const int e = w * 16 + eo;

    __shared__ __align__(16) unsigned short hbuf[2][64];   // bf16 state, dbuf

    // W[h][e][p*16 .. p*16+16) packed to 8 bf16-pair dwords
    unsigned int Wp[8];
    const float* wrow = w_h + ((size_t)(h * 64 + e)) * 64 + p * 16;
#pragma unroll
    for (int j = 0; j < 8; j++) {
        float w0 = wrow[2 * j], w1 = wrow[2 * j + 1];
        Wp[j] = (unsigned int)f2bf(w0) | ((unsigned int)f2bf(w1) << 16);
    }
    const float be = bias[h * 64 + e];
    if (tid < 64) hbuf[0][tid] = f2bf(h0[(b * 16 + h) * 64 + tid]);
    __syncthreads();

    const float* xb = xp + ((size_t)(b * S_) * 16 + h) * 64 + e;  // + t*1024
    unsigned short* yb = y + ((size_t)(b * S_) * 16 + h) * 64 + e;

    float xA[8], xB[8];
#pragma unroll
    for (int i2 = 0; i2 < 8; i2++) xA[i2] = xb[(size_t)i2 * 1024];
#pragma unroll
    for (int i2 = 0; i2 < 8; i2++) xB[i2] = xb[(size_t)(8 + i2) * 1024];

    auto step = [&](int r, int t, float xv) {
        const uint4* hp = (const uint4*)(hbuf[r] + p * 16);  // 32 B slice
        uint4 h0v = hp[0], h1v = hp[1];                      // 2x ds_read_b128
        float a0 = dot2bf(Wp[0], h0v.x, 0.f);
        float a1 = dot2bf(Wp[1], h0v.y, 0.f);
        float a2 = dot2bf(Wp[2], h0v.z, 0.f);
        float a3 = dot2bf(Wp[3], h0v.w, 0.f);
        a0 = dot2bf(Wp[4], h1v.x, a0);
        a1 = dot2bf(Wp[5], h1v.y, a1);
        a2 = dot2bf(Wp[6], h1v.z, a2);
        a3 = dot2bf(Wp[7], h1v.w, a3);
        float sum = (a0 + a1) + (a2 + a3);
        sum = qadd<0xB1>(sum);   // quad_perm [1,0,3,2]
        sum = qadd<0x4E>(sum);   // quad_perm [2,3,0,1] -> all 4 lanes have total
        float pre = (sum + be) + xv;
        // tanh: em = 2^(-2*log2e*|pre|); hn = sign * (1-em)/(1+em)
        float em = __builtin_amdgcn_exp2f(fabsf(pre) * -2.885390081777927f);
        float rr = (1.0f - em) * __builtin_amdgcn_rcpf(1.0f + em);
        float hn = copysignf(rr, pre);
        unsigned short hv = f2bf(hn);
        if (p == 0) {
            hbuf[1 - r][e] = hv;           // ds_write_b16
            yb[(size_t)t * 1024] = hv;     // y gets the same bf16 value
        }
        // raw barrier: drain own DS ops (lgkmcnt), sync waves. NOT
        // __syncthreads(): no vmcnt(0) drain -> x prefetch / y stores stay
        // outstanding across steps.
        asm volatile("s_waitcnt lgkmcnt(0)\n\ts_barrier" ::: "memory");
    };

    for (int t0 = 0; t0 < S_; t0 += 16) {
#pragma unroll
        for (int u = 0; u < 8; u++) step(u & 1, t0 + u, xA[u]);
        if (t0 + 16 < S_) {
#pragma unroll
            for (int i2 = 0; i2 < 8; i2++) xA[i2] = xb[(size_t)(t0 + 16 + i2) * 1024];
        }
#pragma unroll
        for (int u = 0; u < 8; u++) step(u & 1, t0 + 8 + u, xB[u]);
        if (t0 + 24 < S_) {
#pragma unroll
            for (int i2 = 0; i2 < 8; i2++) xB[i2] = xb[(size_t)(t0 + 24 + i2) * 1024];
        }
    }
}

extern "C" void kernel_launch(void* const* d_in, const int* in_sizes, int n_in,
                              void* d_out, int out_size, void* d_ws, size_t ws_size,
                              hipStream_t stream) {
    const float* x     = (const float*)d_in[0];  // [B,S,IN]
    const float* h0    = (const float*)d_in[1];  // [B,H,D]
    const float* w_in  = (const float*)d_in[2];  // [HD,IN]
    const float* w_h   = (const float*)d_in[3];  // [H,D,D]
    const float* bias  = (const float*)d_in[4];  // [H,D]
    const float* w_out = (const float*)d_in[5];  // [OUT,HD]
    float* out = (float*)d_out;                  // [B,S,OUT] fp32; doubles as xp scratch

    char* ws = (char*)d_ws;
    unsigned short* x_bf    = (unsigned short*)(ws);                       // 33.5 MB
    unsigned short* win_bf  = (unsigned short*)(ws + (size_t)33554432);    // 2 MB
    unsigned short* wout_bf = (unsigned short*)(ws + (size_t)35651584);    // 2 MB
    unsigned short* y_bf    = (unsigned short*)(ws + (size_t)37748736);    // 33.5 MB

    {
        int n4 = (M_ * IN_) / 4;
        cast_f32_bf16<<<(n4 + 255) / 256, 256, 0, stream>>>(x, x_bf, n4);
        int w4 = (HD_ * IN_) / 4;
        cast_f32_bf16<<<(w4 + 255) / 256, 256, 0, stream>>>(w_in, win_bf, w4);
        cast_f32_bf16<<<(w4 + 255) / 256, 256, 0, stream>>>(w_out, wout_bf, w4);
    }
    // GEMM1: xp = x @ w_in^T  -> stored in d_out as scratch
    dim3 g1(HD_ / 128, M_ / 128);
    gemm_bt<<<g1, 256, 0, stream>>>(x_bf, win_bf, out, M_, HD_, IN_);
    // sequential scan: reads xp (d_out), writes y_bf
    rnn_scan<<<64, 256, 0, stream>>>(out, w_h, bias, h0, y_bf);
    // GEMM2: out = y @ w_out^T  -> overwrites d_out
    dim3 g2(OUT_ / 128, M_ / 128);
    gemm_bt<<<g2, 256, 0, stream>>>(y_bf, wout_bf, out, M_, OUT_, HD_);
}

// Round 6
// 984.560 us; speedup vs baseline: 1.5340x; 1.1148x over previous
//
#include <hip/hip_runtime.h>

#define B_ 4
#define S_ 4096
#define IN_ 1024
#define H_ 16
#define D_ 64
#define OUT_ 1024
#define HD_ 1024   // H*D
#define M_ 16384   // B*S

typedef __bf16 bf16x8 __attribute__((ext_vector_type(8)));
typedef __bf16 bf16x2 __attribute__((ext_vector_type(2)));
typedef float floatx4 __attribute__((ext_vector_type(4)));

static __device__ __forceinline__ unsigned int f2bf(float f) {
    unsigned int u = __builtin_bit_cast(unsigned int, f);
    u += 0x7fffu + ((u >> 16) & 1u);   // round-to-nearest-even
    return u >> 16;
}

// v_dot2_f32_bf16: c += a.x*b.x + a.y*b.y  (bf16 pairs in, fp32 acc)
static __device__ __forceinline__ float dot2bf(unsigned int a, unsigned int b, float c) {
    return __builtin_amdgcn_fdot2_f32_bf16(__builtin_bit_cast(bf16x2, a),
                                           __builtin_bit_cast(bf16x2, b), c, false);
}

// ---------------- cast fp32 -> bf16, vectorized x4 ----------------
__global__ void cast_f32_bf16(const float* __restrict__ src,
                              unsigned short* __restrict__ dst, int n4) {
    int i = blockIdx.x * blockDim.x + threadIdx.x;
    if (i < n4) {
        float4 v = ((const float4*)src)[i];
        ushort4 o;
        o.x = (unsigned short)f2bf(v.x); o.y = (unsigned short)f2bf(v.y);
        o.z = (unsigned short)f2bf(v.z); o.w = (unsigned short)f2bf(v.w);
        ((ushort4*)dst)[i] = o;
    }
}

// ---------------- bf16 MFMA GEMM: C[M,N] = A[M,K] * B[N,K]^T ----------------
#define LSTR 40
__global__ __launch_bounds__(256) void gemm_bt(
    const unsigned short* __restrict__ A,   // [M,K] bf16
    const unsigned short* __restrict__ Bm,  // [N,K] bf16
    float* __restrict__ C, int M, int N, int K) {
    __shared__ unsigned short As[128 * LSTR];
    __shared__ unsigned short Bs[128 * LSTR];
    const int t = threadIdx.x;
    const int lane = t & 63;
    const int wave = t >> 6;
    const int wm = wave >> 1, wn = wave & 1;
    const int m0 = blockIdx.y * 128;
    const int n0 = blockIdx.x * 128;
    const int l16 = lane & 15;
    const int quad = lane >> 4;

    floatx4 acc[4][4];
#pragma unroll
    for (int i = 0; i < 4; i++)
#pragma unroll
        for (int j = 0; j < 4; j++) acc[i][j] = (floatx4){0.f, 0.f, 0.f, 0.f};

    for (int k0 = 0; k0 < K; k0 += 32) {
#pragma unroll
        for (int it = 0; it < 2; it++) {
            int c = it * 256 + t;
            int row = c >> 2;
            int kc = c & 3;
            uint4 va = *(const uint4*)(A + (size_t)(m0 + row) * K + k0 + kc * 8);
            *(uint4*)(As + row * LSTR + kc * 8) = va;
            uint4 vb = *(const uint4*)(Bm + (size_t)(n0 + row) * K + k0 + kc * 8);
            *(uint4*)(Bs + row * LSTR + kc * 8) = vb;
        }
        __syncthreads();
        bf16x8 af[4], bfr[4];
#pragma unroll
        for (int i = 0; i < 4; i++)
            af[i] = *(const bf16x8*)(As + (wm * 64 + i * 16 + l16) * LSTR + quad * 8);
#pragma unroll
        for (int j = 0; j < 4; j++)
            bfr[j] = *(const bf16x8*)(Bs + (wn * 64 + j * 16 + l16) * LSTR + quad * 8);
#pragma unroll
        for (int i = 0; i < 4; i++)
#pragma unroll
            for (int j = 0; j < 4; j++)
                acc[i][j] = __builtin_amdgcn_mfma_f32_16x16x32_bf16(
                    af[i], bfr[j], acc[i][j], 0, 0, 0);
        __syncthreads();
    }
#pragma unroll
    for (int i = 0; i < 4; i++)
#pragma unroll
        for (int j = 0; j < 4; j++)
#pragma unroll
            for (int r = 0; r < 4; r++) {
                int row = m0 + wm * 64 + i * 16 + quad * 4 + r;
                int col = n0 + wn * 64 + j * 16 + l16;
                C[(size_t)row * N + col] = acc[i][j][r];
            }
}

// ---------------- sequential RNN scan (v6: all-register, readlane bcast) ----
// 64 blocks (one (b,h) chain), ONE wave. Lane e owns h[e] (bf16 in a VGPR).
// Per step: pack adjacent-lane bf16 pairs (1 DPP quad_perm + 1 lshl_or),
// broadcast the 32 pairs via v_readlane -> SGPRs, and each lane computes its
// full 64-dot with 32 v_dot2_f32_bf16 (SGPR src0 = broadcast h pair, VGPR
// src1 = its W row pair). NO LDS, NO barrier, no lgkm waits on the serial
// path — the v3/v5 ~500cyc/step barrier+LDS-latency floor is gone; this is
// pure VALU issue (~87 instr/step).
__global__ __launch_bounds__(64, 1) void rnn_scan(
    const float* __restrict__ xp,      // [B,S,H,D] fp32 (GEMM1 output)
    const float* __restrict__ w_h,     // [H,D,D]
    const float* __restrict__ bias,    // [H,D]
    const float* __restrict__ h0,      // [B,H,D]
    unsigned short* __restrict__ y) {  // [B,S,H,D] bf16
    const int bh = blockIdx.x;
    const int b = bh >> 4;
    const int h = bh & 15;
    const int e = threadIdx.x;

    // W[h][e][0..63] packed into 32 bf16-pair dwords
    unsigned int W2[32];
    const float* wrow = w_h + ((size_t)(h * 64 + e)) * 64;
#pragma unroll
    for (int j = 0; j < 16; j++) {
        float4 v = ((const float4*)wrow)[j];
        W2[2 * j]     = f2bf(v.x) | (f2bf(v.y) << 16);
        W2[2 * j + 1] = f2bf(v.z) | (f2bf(v.w) << 16);
    }
    const float be = bias[h * 64 + e];
    unsigned int hb = f2bf(h0[(b * 16 + h) * 64 + e]);   // bf16 state, 1/lane

    const float* xb = xp + ((size_t)(b * S_) * 16 + h) * 64 + e;  // + t*1024
    unsigned short* yb = y + ((size_t)(b * S_) * 16 + h) * 64 + e;

    float xA[8], xB[8];
#pragma unroll
    for (int i2 = 0; i2 < 8; i2++) xA[i2] = xb[(size_t)i2 * 1024];
#pragma unroll
    for (int i2 = 0; i2 < 8; i2++) xB[i2] = xb[(size_t)(8 + i2) * 1024];

    auto step = [&](int t, float xv) {
        // quad_perm [1,1,3,3] (0xF5): lane i gets h from lane i+1 (even i)
        // or its own (odd i) -> even lane 2k packs (h[2k], h[2k+1]).
        unsigned int hbs = (unsigned int)__builtin_amdgcn_update_dpp(
            0, (int)hb, 0xF5, 0xF, 0xF, true);
        unsigned int pk = (hbs << 16) | hb;
        float a0 = 0.f, a1 = 0.f, a2 = 0.f, a3 = 0.f;
#pragma unroll
        for (int k = 0; k < 8; k++) {
            // v_readlane -> SGPR: hardware broadcast, no LDS
            unsigned int s0 = (unsigned int)__builtin_amdgcn_readlane((int)pk, 8 * k + 0);
            unsigned int s1 = (unsigned int)__builtin_amdgcn_readlane((int)pk, 8 * k + 2);
            unsigned int s2 = (unsigned int)__builtin_amdgcn_readlane((int)pk, 8 * k + 4);
            unsigned int s3 = (unsigned int)__builtin_amdgcn_readlane((int)pk, 8 * k + 6);
            a0 = dot2bf(s0, W2[4 * k + 0], a0);
            a1 = dot2bf(s1, W2[4 * k + 1], a1);
            a2 = dot2bf(s2, W2[4 * k + 2], a2);
            a3 = dot2bf(s3, W2[4 * k + 3], a3);
        }
        float sum = (a0 + a1) + (a2 + a3);
        float pre = sum + (be + xv);
        // tanh: em = 2^(-2*log2e*|pre|); hn = sign * (1-em)/(1+em)
        float em = __builtin_amdgcn_exp2f(fabsf(pre) * -2.885390081777927f);
        float rr = (1.0f - em) * __builtin_amdgcn_rcpf(1.0f + em);
        float hn = copysignf(rr, pre);
        hb = f2bf(hn);
        yb[(size_t)t * 1024] = (unsigned short)hb;
    };

    for (int t0 = 0; t0 < S_; t0 += 16) {
#pragma unroll
        for (int u = 0; u < 8; u++) step(t0 + u, xA[u]);
        if (t0 + 16 < S_) {
#pragma unroll
            for (int i2 = 0; i2 < 8; i2++) xA[i2] = xb[(size_t)(t0 + 16 + i2) * 1024];
        }
#pragma unroll
        for (int u = 0; u < 8; u++) step(t0 + 8 + u, xB[u]);
        if (t0 + 24 < S_) {
#pragma unroll
            for (int i2 = 0; i2 < 8; i2++) xB[i2] = xb[(size_t)(t0 + 24 + i2) * 1024];
        }
    }
}

extern "C" void kernel_launch(void* const* d_in, const int* in_sizes, int n_in,
                              void* d_out, int out_size, void* d_ws, size_t ws_size,
                              hipStream_t stream) {
    const float* x     = (const float*)d_in[0];  // [B,S,IN]
    const float* h0    = (const float*)d_in[1];  // [B,H,D]
    const float* w_in  = (const float*)d_in[2];  // [HD,IN]
    const float* w_h   = (const float*)d_in[3];  // [H,D,D]
    const float* bias  = (const float*)d_in[4];  // [H,D]
    const float* w_out = (const float*)d_in[5];  // [OUT,HD]
    float* out = (float*)d_out;                  // [B,S,OUT] fp32; doubles as xp scratch

    char* ws = (char*)d_ws;
    unsigned short* x_bf    = (unsigned short*)(ws);                       // 33.5 MB
    unsigned short* win_bf  = (unsigned short*)(ws + (size_t)33554432);    // 2 MB
    unsigned short* wout_bf = (unsigned short*)(ws + (size_t)35651584);    // 2 MB
    unsigned short* y_bf    = (unsigned short*)(ws + (size_t)37748736);    // 33.5 MB

    {
        int n4 = (M_ * IN_) / 4;
        cast_f32_bf16<<<(n4 + 255) / 256, 256, 0, stream>>>(x, x_bf, n4);
        int w4 = (HD_ * IN_) / 4;
        cast_f32_bf16<<<(w4 + 255) / 256, 256, 0, stream>>>(w_in, win_bf, w4);
        cast_f32_bf16<<<(w4 + 255) / 256, 256, 0, stream>>>(w_out, wout_bf, w4);
    }
    // GEMM1: xp = x @ w_in^T  -> stored in d_out as scratch
    dim3 g1(HD_ / 128, M_ / 128);
    gemm_bt<<<g1, 256, 0, stream>>>(x_bf, win_bf, out, M_, HD_, IN_);
    // sequential scan: reads xp (d_out), writes y_bf
    rnn_scan<<<64, 64, 0, stream>>>(out, w_h, bias, h0, y_bf);
    // GEMM2: out = y @ w_out^T  -> overwrites d_out
    dim3 g2(OUT_ / 128, M_ / 128);
    gemm_bt<<<g2, 256, 0, stream>>>(y_bf, wout_bf, out, M_, OUT_, HD_);
}